// Round 18
// baseline (268.718 us; speedup 1.0000x reference)
//
#include <hip/hip_runtime.h>
#include <stdint.h>

typedef unsigned short u16;
typedef __attribute__((ext_vector_type(4))) float f32x4;
typedef _Float16 h16;
typedef __attribute__((ext_vector_type(8))) _Float16 f16x8;   // 8 x fp16
typedef __attribute__((ext_vector_type(4))) _Float16 h16x4;
typedef __attribute__((ext_vector_type(2))) __fp16 fp16v2;    // builtin-native fp16 pair

#define DMODEL 1024
#define SEQ    2048
#define BATCH  4
#define NHEAD  16
#define DH     64
#define NTOK   (BATCH*SEQ)
#define BH     (BATCH*NHEAD)
#define EPS    1e-5f
#define LOG2E  1.44269504f

__device__ __forceinline__ void gload_lds16(const void* g, void* l){
  __builtin_amdgcn_global_load_lds((__attribute__((address_space(1))) unsigned int*)g,
                                   (__attribute__((address_space(3))) unsigned int*)l,
                                   16, 0, 0);
}

__device__ __forceinline__ float fastexp2(float x){
#if __has_builtin(__builtin_amdgcn_exp2f)
  return __builtin_amdgcn_exp2f(x);
#else
  return exp2f(x);
#endif
}

// swizzle key for 128B-row tiles (8 chunks of 16B per row)
__device__ __forceinline__ int swzkey(int row){ return (row&7) ^ ((row>>3)&7); }

// ---------------- fused: weight->fp16 prep (ids 0..5119) + LayerNorm1 (ids 5120..7167) ----------------
__global__ __launch_bounds__(256) void prep_ln(const float* __restrict__ Wq,
                                               const float* __restrict__ Wk,
                                               const float* __restrict__ Wv,
                                               const float* __restrict__ W1,
                                               const float* __restrict__ W2,
                                               h16* __restrict__ wqkv,
                                               h16* __restrict__ w1h,
                                               h16* __restrict__ w2h,
                                               const float* __restrict__ x,
                                               const float* __restrict__ sc,
                                               const float* __restrict__ bi,
                                               h16* __restrict__ xn_h){
  int id = blockIdx.x;
  int t = threadIdx.x;
  if (id < 5120){
    const int nW = DMODEL*DMODEL;
    int r = id >> 10;
    int i = ((id & 1023)*256 + t)*4;
    const float* src = (r==0) ? Wq : (r==1) ? Wk : (r==2) ? Wv : (r==3) ? W1 : W2;
    h16* dst = (r==0) ? wqkv : (r==1) ? (wqkv+nW) : (r==2) ? (wqkv+2*nW) : (r==3) ? w1h : w2h;
    float4 v = *reinterpret_cast<const float4*>(src + i);
    h16x4 o; o[0]=(h16)v.x; o[1]=(h16)v.y; o[2]=(h16)v.z; o[3]=(h16)v.w;
    *reinterpret_cast<h16x4*>(dst + i) = o;
    return;
  }
  int row = (id - 5120)*4 + (t>>6);
  int l = t & 63;
  size_t rbase = (size_t)row*DMODEL;
  float v[16];
  #pragma unroll
  for (int q=0;q<4;++q){
    float4 tt = *reinterpret_cast<const float4*>(x + rbase + q*256 + l*4);
    v[q*4]=tt.x; v[q*4+1]=tt.y; v[q*4+2]=tt.z; v[q*4+3]=tt.w;
  }
  float s=0.f, ss=0.f;
  #pragma unroll
  for (int j=0;j<16;++j){ s += v[j]; ss += v[j]*v[j]; }
  #pragma unroll
  for (int m=1;m<64;m<<=1){ s += __shfl_xor(s,m); ss += __shfl_xor(ss,m); }
  float mu  = s * (1.0f/DMODEL);
  float var = fmaxf(ss * (1.0f/DMODEL) - mu*mu, 0.0f);
  float r = rsqrtf(var + EPS);
  #pragma unroll
  for (int q=0;q<4;++q){
    float4 g = *reinterpret_cast<const float4*>(sc + q*256 + l*4);
    float4 b = *reinterpret_cast<const float4*>(bi + q*256 + l*4);
    h16x4 oh;
    oh[0] = (h16)((v[q*4  ]-mu)*r*g.x + b.x);
    oh[1] = (h16)((v[q*4+1]-mu)*r*g.y + b.y);
    oh[2] = (h16)((v[q*4+2]-mu)*r*g.z + b.z);
    oh[3] = (h16)((v[q*4+3]-mu)*r*g.w + b.w);
    *reinterpret_cast<h16x4*>(xn_h + rbase + q*256 + l*4) = oh;
  }
}

// ---------------- fused QKV GEMM (fp16, BK=64, double-buffered, XCD-stripe bn-major) ----------------
__global__ __launch_bounds__(256) void gemm_qkv(const h16* __restrict__ xn,
                                                const h16* __restrict__ wqkv,
                                                h16* __restrict__ qT,
                                                h16* __restrict__ kR,
                                                h16* __restrict__ vT){
  const int K = DMODEL;
  __shared__ h16 As[2][128*64], Bs[2][128*64];
  int id = blockIdx.x;
  int xcd = id & 7, j = id >> 3;
  int bn = j >> 3;                       // bn-major: A-stripe (2MB) stays L2-resident
  int bm = xcd*8 + (j & 7);
  int t = threadIdx.x, l = t&63, w = t>>6;
  int wr = w>>1, wc = w&1;
  const h16* Bsrc = wqkv + (size_t)bn*128*K;

  f32x4 acc[4][4];
  #pragma unroll
  for (int m=0;m<4;++m)
    #pragma unroll
    for (int n=0;n<4;++n)
      #pragma unroll
      for (int i=0;i<4;++i) acc[m][n][i] = 0.0f;

  #define QSTAGE(bb, k0)                                                          \
    { _Pragma("unroll")                                                           \
      for (int i_=0;i_<4;++i_){                                                   \
        int slot = i_*256 + t;                                                    \
        int row = slot>>3, pc = slot&7;                                           \
        int lc = pc ^ swzkey(row);                                                \
        gload_lds16(xn + (size_t)(bm*128 + row)*K + (k0) + lc*8, &As[bb][slot*8]);\
        gload_lds16(Bsrc + (size_t)row*K + (k0) + lc*8, &Bs[bb][slot*8]);         \
      } }

  const int nk = K/64;
  QSTAGE(0, 0);
  int cur = 0;
  for (int kt=0; kt<nk; ++kt){
    __syncthreads();                 // vmcnt drain: buf[cur] staged; prev compute done
    if (kt+1 < nk) QSTAGE(cur^1, (kt+1)*64);
    #pragma unroll
    for (int ks=0; ks<2; ++ks){
      f16x8 af[4], bf[4];
      #pragma unroll
      for (int m=0;m<4;++m){
        int row = wr*64 + m*16 + (l&15);
        int cp = (ks*4 + (l>>4)) ^ swzkey(row);
        af[m] = *reinterpret_cast<const f16x8*>(&As[cur][row*64 + cp*8]);
      }
      #pragma unroll
      for (int n=0;n<4;++n){
        int row = wc*64 + n*16 + (l&15);
        int cp = (ks*4 + (l>>4)) ^ swzkey(row);
        bf[n] = *reinterpret_cast<const f16x8*>(&Bs[cur][row*64 + cp*8]);
      }
      __builtin_amdgcn_s_setprio(1);
      #pragma unroll
      for (int m=0;m<4;++m)
        #pragma unroll
        for (int n=0;n<4;++n)
          acc[m][n] = __builtin_amdgcn_mfma_f32_16x16x32_f16(af[m], bf[n], acc[m][n], 0,0,0);
      __builtin_amdgcn_s_setprio(0);
    }
    cur ^= 1;
  }

  // epilogue
  const bool isK = (bn >= 8 && bn < 16);
  const bool isQ = (bn < 8);
  #pragma unroll
  for (int m=0;m<4;++m){
    int row0 = bm*128 + wr*64 + m*16 + ((l>>4)<<2);
    int b = row0 >> 11, s0 = row0 & 2047;
    #pragma unroll
    for (int n=0;n<4;++n){
      int col = bn*128 + wc*64 + n*16 + (l&15);
      int dg = col & 1023;
      int hh = dg >> 6, dh = dg & 63;
      if (isK){
        #pragma unroll
        for (int i=0;i<4;++i)
          kR[((size_t)(b*NHEAD + hh)*SEQ + s0 + i)*DH + dh] = (h16)acc[m][n][i];
      } else {
        h16x4 ov;
        #pragma unroll
        for (int i=0;i<4;++i){
          float vv = acc[m][n][i];
          if (isQ) vv *= LOG2E;
          ov[i] = (h16)vv;
        }
        // sigma-permute s for V: within 32-group, pos = (c&3) + (c>>2)*8 + h*4
        int s0p = isQ ? s0 : ((s0 & ~31) + (((s0>>2)&3)<<3) + (((s0>>4)&1)<<2));
        h16* dst = (isQ ? qT : vT) + ((size_t)(b*NHEAD + hh)*DH + dh)*SEQ + s0p;
        *reinterpret_cast<h16x4*>(dst) = ov;
      }
    }
  }
}

// ---------------- fp16 GEMM (FFN): 512 threads, 8 waves (2x4), 128x128, BK=64, dbuf ----------------
template<bool RELU, bool RES, bool OUTF32>
__global__ __launch_bounds__(512) void gemm_ffn(const h16* __restrict__ A,
                                                const h16* __restrict__ W,
                                                const float* __restrict__ bias,
                                                const h16* __restrict__ resid,
                                                void* __restrict__ outp,
                                                int M, int N, int K){
  __shared__ h16 As[2][128*64];
  __shared__ h16 Bs[2][128*64];
  int id = blockIdx.x;
  int xcd = id & 7, j = id >> 3;
  int spb = (M>>7)>>3;                   // stripe blocks per xcd (8)
  int bn = j / spb;                      // bn-major
  int bm = xcd*spb + (j - bn*spb);
  int t = threadIdx.x, l = t&63, w = t>>6;
  int wr = w>>2, wc = w&3;               // 2 x 4 wave grid; wave owns 64x32
  f32x4 acc[4][2];
  #pragma unroll
  for (int m=0;m<4;++m)
    #pragma unroll
    for (int n=0;n<2;++n)
      #pragma unroll
      for (int i=0;i<4;++i) acc[m][n][i] = 0.0f;

  #define FSTAGE(bb, k0)                                                          \
    { _Pragma("unroll")                                                           \
      for (int i_=0;i_<2;++i_){                                                   \
        int slot = i_*512 + t;                                                    \
        int row = slot>>3, pc = slot&7;                                           \
        int lc = pc ^ swzkey(row);                                                \
        gload_lds16(A + (size_t)(bm*128 + row)*K + (k0) + lc*8, &As[bb][slot*8]); \
        gload_lds16(W + (size_t)(bn*128 + row)*K + (k0) + lc*8, &Bs[bb][slot*8]); \
      } }

  const int nk = K/64;
  FSTAGE(0, 0);
  int cur = 0;
  for (int kt=0; kt<nk; ++kt){
    __syncthreads();
    if (kt+1 < nk) FSTAGE(cur^1, (kt+1)*64);
    #pragma unroll
    for (int ks=0; ks<2; ++ks){
      f16x8 af[4], bf[2];
      #pragma unroll
      for (int m=0;m<4;++m){
        int row = wr*64 + m*16 + (l&15);
        int cp = (ks*4 + (l>>4)) ^ swzkey(row);
        af[m] = *reinterpret_cast<const f16x8*>(&As[cur][row*64 + cp*8]);
      }
      #pragma unroll
      for (int n=0;n<2;++n){
        int row = wc*32 + n*16 + (l&15);
        int cp = (ks*4 + (l>>4)) ^ swzkey(row);
        bf[n] = *reinterpret_cast<const f16x8*>(&Bs[cur][row*64 + cp*8]);
      }
      __builtin_amdgcn_s_setprio(1);
      #pragma unroll
      for (int m=0;m<4;++m)
        #pragma unroll
        for (int n=0;n<2;++n)
          acc[m][n] = __builtin_amdgcn_mfma_f32_16x16x32_f16(af[m], bf[n], acc[m][n], 0,0,0);
      __builtin_amdgcn_s_setprio(0);
    }
    cur ^= 1;
  }

  #pragma unroll
  for (int m=0;m<4;++m){
    int row0 = bm*128 + wr*64 + m*16 + ((l>>4)<<2);
    #pragma unroll
    for (int n=0;n<2;++n){
      int col = bn*128 + wc*32 + n*16 + (l&15);
      float bv = bias[col];
      #pragma unroll
      for (int i=0;i<4;++i){
        float vv = acc[m][n][i] + bv;
        if (RELU) vv = fmaxf(vv, 0.0f);
        size_t off = (size_t)(row0+i)*N + col;
        if (RES) vv += (float)resid[off];
        if (OUTF32) ((float*)outp)[off] = vv;
        else        ((h16*)outp)[off] = (h16)vv;
      }
    }
  }
}

// ---------------- flash attention v10 (r15-proven): ones-MFMA psum, shuffle-free defer ----------------
#define QBLK 256
#define KBLK 64
#define RESC_THR_L2 11.5415603f    // 8 * log2(e)
#define NROWS (BH*8*256)           // 131072 rows per half

__global__ __launch_bounds__(512, 2) void attn_split(const h16* __restrict__ qT,
                                                     const h16* __restrict__ kR,
                                                     const h16* __restrict__ vT,
                                                     h16* __restrict__ outP0,
                                                     h16* __restrict__ outP1,
                                                     float2* __restrict__ lm){
  int id = blockIdx.x;
  int bh   = (id & 7) + ((id >> 7) << 3);   // XCD-aware: same bh stays on one XCD
  int qb   = (id >> 3) & 7;
  int half = (id >> 6) & 1;
  int t = threadIdx.x, l = t&63, w = t>>6;
  int g = l>>4;

  const size_t hbase = (size_t)bh * SEQ * DH;
  const h16* khb = kR + hbase + (size_t)half*(SEQ/2)*DH;   // [s][64], row offset
  const h16* qtb = qT + hbase;                             // [64][s]
  const h16* vtb = vT + hbase + half*(SEQ/2);              // [64][s], col offset
  int q0 = qb*QBLK + w*32;

  // Q fragments (B-operand), log2e-scaled
  f16x8 qf[2][2];
  #pragma unroll
  for (int qs=0;qs<2;++qs)
    #pragma unroll
    for (int kc=0;kc<2;++kc)
      #pragma unroll
      for (int j=0;j<8;++j)
        qf[qs][kc][j] = qtb[(size_t)(kc*32 + g*8 + j)*SEQ + q0 + qs*16 + (l&15)];

  __shared__ h16 Kh2[2][KBLK*64];
  __shared__ h16 Vt2[2][KBLK*64];

  // hoisted LDS byte-offsets: identical formula for K (st) and V (dt) reads
  int offs[8];
  #pragma unroll
  for (int kc=0;kc<2;++kc)
    #pragma unroll
    for (int st=0;st<4;++st){
      int rr = st*16 + (l&15);
      offs[kc*4+st] = rr*128 + (((kc*4 + g) ^ swzkey(rr))<<4);
    }

  // hoisted staging source pointers (advance per tile)
  int srow = t>>3, spc = t&7;
  int slc = spc ^ swzkey(srow);
  const h16* ksrc = khb + (size_t)srow*DH + slc*8;
  const h16* vsrc = vtb + (size_t)srow*SEQ + slc*8;

  f32x4 o[2][4];
  #pragma unroll
  for (int qs=0;qs<2;++qs)
    #pragma unroll
    for (int dt=0;dt<4;++dt)
      #pragma unroll
      for (int i=0;i<4;++i) o[qs][dt][i] = 0.0f;
  // psum accumulators via ones-MFMA (full 64-k sum per tile; identical across partner lanes)
  f32x4 lacc[2];
  #pragma unroll
  for (int qs=0;qs<2;++qs)
    #pragma unroll
    for (int i=0;i<4;++i) lacc[qs][i] = 0.0f;
  float m_run[2] = {-3.0e38f, -3.0e38f};

  f16x8 onesA;
  #pragma unroll
  for (int j=0;j<8;++j) onesA[j] = (h16)1.0f;

  #define STAGE(bb)                                  \
    { gload_lds16(ksrc, &Kh2[bb][t*8]);              \
      gload_lds16(vsrc, &Vt2[bb][t*8]);              \
      ksrc += KBLK*DH; vsrc += KBLK; }

  STAGE(0);
  int cur = 0;
  const int NT = SEQ/2/KBLK;     // 16 tiles per half
  for (int kt=0; kt<NT; ++kt){
    __syncthreads();
    if (kt+1 < NT) STAGE(cur^1);

    char* KhB = (char*)&Kh2[cur][0];
    char* VtB = (char*)&Vt2[cur][0];

    // ---- S^T = K.Q^T (fp16, log2 domain) ----
    f32x4 sc[2][4];
    #pragma unroll
    for (int qs=0;qs<2;++qs)
      #pragma unroll
      for (int st=0;st<4;++st)
        #pragma unroll
        for (int i=0;i<4;++i) sc[qs][st][i] = 0.0f;

    __builtin_amdgcn_s_setprio(1);
    #pragma unroll
    for (int kc=0;kc<2;++kc)
      #pragma unroll
      for (int st=0;st<4;++st){
        f16x8 kf = *reinterpret_cast<const f16x8*>(KhB + offs[kc*4+st]);
        sc[0][st] = __builtin_amdgcn_mfma_f32_16x16x32_f16(kf, qf[0][kc], sc[0][st], 0,0,0);
        sc[1][st] = __builtin_amdgcn_mfma_f32_16x16x32_f16(kf, qf[1][kc], sc[1][st], 0,0,0);
      }
    __builtin_amdgcn_s_setprio(0);

    // ---- defer check: per-lane local max only (wave-AND == per-row check) ----
    float lmax[2];
    #pragma unroll
    for (int qs=0;qs<2;++qs){
      const float* s = (const float*)&sc[qs][0];
      float m0 = fmaxf(s[0], s[1]);
      #pragma unroll
      for (int j=2;j<16;j+=2) m0 = fmaxf(fmaxf(m0, s[j]), s[j+1]);  // folds to v_max3
      lmax[qs] = m0;
    }
    bool defer = (__all((lmax[0] <= m_run[0] + RESC_THR_L2) &&
                        (lmax[1] <= m_run[1] + RESC_THR_L2)) != 0);
    if (!defer){
      #pragma unroll
      for (int qs=0;qs<2;++qs){
        float m0 = lmax[qs];
        m0 = fmaxf(m0, __shfl_xor(m0, 16));
        m0 = fmaxf(m0, __shfl_xor(m0, 32));
        float mn = fmaxf(m_run[qs], m0);
        float scl = fastexp2(m_run[qs] - mn);
        m_run[qs] = mn;
        #pragma unroll
        for (int dt=0;dt<4;++dt)
          #pragma unroll
          for (int i=0;i<4;++i) o[qs][dt][i] *= scl;
        #pragma unroll
        for (int i=0;i<4;++i) lacc[qs][i] *= scl;
      }
    }

    // ---- P = 2^(s - m_run), packed to fp16 ----
    union { unsigned u[4]; f16x8 v; } pfu[2][2];
    #pragma unroll
    for (int qs=0;qs<2;++qs){
      float mn = m_run[qs];
      const float* s = (const float*)&sc[qs][0];
      #pragma unroll
      for (int kc=0;kc<2;++kc)
        #pragma unroll
        for (int j=0;j<4;++j){
          float p0 = fastexp2(s[kc*8+2*j]   - mn);
          float p1 = fastexp2(s[kc*8+2*j+1] - mn);
          union { fp16v2 v2; unsigned u; } c;
          c.v2 = __builtin_amdgcn_cvt_pkrtz(p0, p1);
          pfu[qs][kc].u[j] = c.u;
        }
    }

    // ---- PV + psum: O^T += V^T . P^T; lacc += ones . P^T ----
    __builtin_amdgcn_s_setprio(1);
    #pragma unroll
    for (int kc=0;kc<2;++kc){
      lacc[0] = __builtin_amdgcn_mfma_f32_16x16x32_f16(onesA, pfu[0][kc].v, lacc[0], 0,0,0);
      lacc[1] = __builtin_amdgcn_mfma_f32_16x16x32_f16(onesA, pfu[1][kc].v, lacc[1], 0,0,0);
      #pragma unroll
      for (int dt=0;dt<4;++dt){
        f16x8 vf = *reinterpret_cast<const f16x8*>(VtB + offs[kc*4+dt]);
        o[0][dt] = __builtin_amdgcn_mfma_f32_16x16x32_f16(vf, pfu[0][kc].v, o[0][dt], 0,0,0);
        o[1][dt] = __builtin_amdgcn_mfma_f32_16x16x32_f16(vf, pfu[1][kc].v, o[1][dt], 0,0,0);
      }
    }
    __builtin_amdgcn_s_setprio(0);
    cur ^= 1;
  }

  // epilogue: lacc already holds full row-sum (no cross-lane reduce needed)
  h16* outP = half ? outP1 : outP0;
  int rowbase = (bh*8 + qb)*256 + w*32;
  #pragma unroll
  for (int qs=0;qs<2;++qs){
    float lt = lacc[qs][0];
    float inv = 1.0f / lt;
    int row = rowbase + qs*16 + (l&15);
    #pragma unroll
    for (int dt=0;dt<4;++dt){
      h16x4 ov;
      #pragma unroll
      for (int i=0;i<4;++i) ov[i] = (h16)(o[qs][dt][i] * inv);
      *reinterpret_cast<h16x4*>(outP + (size_t)row*64 + dt*16 + (g<<2)) = ov;
    }
    if (l < 16)
      lm[half*NROWS + row] = make_float2(m_run[qs], lt);
  }
}

// ---------------- fused combine + LayerNorm2 (fp16 residual in, fp16 out) ----------------
__global__ __launch_bounds__(256) void ln2_combine(const h16* __restrict__ xn,
                                                   const h16* __restrict__ p0,
                                                   const h16* __restrict__ p1,
                                                   const float2* __restrict__ lm,
                                                   const float* __restrict__ sc,
                                                   const float* __restrict__ bi,
                                                   h16* __restrict__ oh16){
  int token = blockIdx.x*4 + (threadIdx.x>>6);
  int l = threadIdx.x & 63;
  int b = token >> 11, qb = (token >> 8) & 7, r = token & 255;
  int hh = l >> 2;                       // head owned by this lane group
  int rowg = ((b*NHEAD + hh)*8 + qb)*256 + r;
  float2 A = lm[rowg];
  float2 B = lm[NROWS + rowg];
  float ms = fmaxf(A.x, B.x);
  float w0 = A.y * fastexp2(A.x - ms);
  float w1 = B.y * fastexp2(B.x - ms);
  float inv = 1.0f / (w0 + w1);
  w0 *= inv; w1 *= inv;

  // lane's 16 contiguous d-elements: global d = l*16
  const f16x8* q0 = reinterpret_cast<const f16x8*>(p0 + (size_t)rowg*64 + (l&3)*16);
  const f16x8* q1 = reinterpret_cast<const f16x8*>(p1 + (size_t)rowg*64 + (l&3)*16);
  size_t base = (size_t)token*DMODEL + l*16;
  float v[16];
  #pragma unroll
  for (int c=0;c<2;++c){
    f16x8 a = q0[c], bb = q1[c];
    #pragma unroll
    for (int j=0;j<8;++j)
      v[c*8+j] = (float)a[j]*w0 + (float)bb[j]*w1;
  }
  #pragma unroll
  for (int c=0;c<2;++c){
    f16x8 xv = *reinterpret_cast<const f16x8*>(xn + base + c*8);
    #pragma unroll
    for (int j=0;j<8;++j)
      v[c*8+j] += (float)xv[j];
  }

  float s=0.f, ss=0.f;
  #pragma unroll
  for (int j=0;j<16;++j){ s += v[j]; ss += v[j]*v[j]; }
  #pragma unroll
  for (int m=1;m<64;m<<=1){ s += __shfl_xor(s,m); ss += __shfl_xor(ss,m); }
  float mu  = s * (1.0f/DMODEL);
  float var = fmaxf(ss * (1.0f/DMODEL) - mu*mu, 0.0f);
  float rr = rsqrtf(var + EPS);
  #pragma unroll
  for (int q=0;q<4;++q){
    float4 g = *reinterpret_cast<const float4*>(sc + l*16 + q*4);
    float4 bb = *reinterpret_cast<const float4*>(bi + l*16 + q*4);
    h16x4 oh;
    oh[0] = (h16)((v[q*4  ]-mu)*rr*g.x + bb.x);
    oh[1] = (h16)((v[q*4+1]-mu)*rr*g.y + bb.y);
    oh[2] = (h16)((v[q*4+2]-mu)*rr*g.z + bb.z);
    oh[3] = (h16)((v[q*4+3]-mu)*rr*g.w + bb.w);
    *reinterpret_cast<h16x4*>(oh16 + base + q*4) = oh;
  }
}

// ---------------- launch ----------------
extern "C" void kernel_launch(void* const* d_in, const int* in_sizes, int n_in,
                              void* d_out, int out_size, void* d_ws, size_t ws_size,
                              hipStream_t stream){
  (void)in_sizes; (void)n_in; (void)out_size; (void)ws_size;
  const float* x    = (const float*)d_in[0];
  const float* Wq   = (const float*)d_in[1];
  const float* Wk   = (const float*)d_in[2];
  const float* Wv   = (const float*)d_in[3];
  const float* W1   = (const float*)d_in[4];
  const float* b1   = (const float*)d_in[5];
  const float* W2   = (const float*)d_in[6];
  const float* b2   = (const float*)d_in[7];
  const float* ln1s = (const float*)d_in[8];
  const float* ln1b = (const float*)d_in[9];
  const float* ln2s = (const float*)d_in[10];
  const float* ln2b = (const float*)d_in[11];

  char* ws = (char*)d_ws;
  h16* part0     = (h16*)ws;    ws += (size_t)NTOK*DMODEL*2;
  h16* part1     = (h16*)ws;    ws += (size_t)NTOK*DMODEL*2;
  h16* xn_h      = (h16*)ws;    ws += (size_t)NTOK*DMODEL*2;
  h16* qT_h      = (h16*)ws;    ws += (size_t)NTOK*DMODEL*2;
  h16* k_h       = (h16*)ws;    ws += (size_t)NTOK*DMODEL*2;
  h16* vT_h      = (h16*)ws;    ws += (size_t)NTOK*DMODEL*2;
  h16* xt_h      = (h16*)ws;    ws += (size_t)NTOK*DMODEL*2;
  h16* h_h       = (h16*)ws;    ws += (size_t)NTOK*DMODEL*2;
  h16* wqkv_h    = (h16*)ws;    ws += (size_t)3*DMODEL*DMODEL*2;
  h16* w1h       = (h16*)ws;    ws += (size_t)DMODEL*DMODEL*2;
  h16* w2h       = (h16*)ws;    ws += (size_t)DMODEL*DMODEL*2;
  float2* lm     = (float2*)ws; ws += (size_t)2*NROWS*8;

  prep_ln<<<5120 + NTOK/4, 256, 0, stream>>>(Wq, Wk, Wv, W1, W2, wqkv_h, w1h, w2h,
                                             x, ln1s, ln1b, xn_h);

  gemm_qkv<<<3*DMODEL/128 * (NTOK/128), 256, 0, stream>>>(
      xn_h, wqkv_h, qT_h, k_h, vT_h);

  attn_split<<<BH*(SEQ/QBLK)*2, 512, 0, stream>>>(qT_h, k_h, vT_h, part0, part1, lm);

  ln2_combine<<<NTOK/4, 256, 0, stream>>>(xn_h, part0, part1, lm,
                                          ln2s, ln2b, xt_h);

  gemm_ffn<true,false,false><<<(DMODEL/128) * (NTOK/128), 512, 0, stream>>>(
      xt_h, w1h, b1, nullptr, h_h, NTOK, DMODEL, DMODEL);

  gemm_ffn<false,true,true><<<(DMODEL/128) * (NTOK/128), 512, 0, stream>>>(
      h_h, w2h, b2, xt_h, d_out, NTOK, DMODEL, DMODEL);
}

// Round 19
// 249.911 us; speedup vs baseline: 1.0753x; 1.0753x over previous
//
#include <hip/hip_runtime.h>
#include <stdint.h>

typedef unsigned short u16;
typedef __attribute__((ext_vector_type(4))) float f32x4;
typedef _Float16 h16;
typedef __attribute__((ext_vector_type(8))) _Float16 f16x8;   // 8 x fp16
typedef __attribute__((ext_vector_type(4))) _Float16 h16x4;
typedef __attribute__((ext_vector_type(2))) __fp16 fp16v2;    // builtin-native fp16 pair

#define DMODEL 1024
#define SEQ    2048
#define BATCH  4
#define NHEAD  16
#define DH     64
#define NTOK   (BATCH*SEQ)
#define BH     (BATCH*NHEAD)
#define EPS    1e-5f
#define LOG2E  1.44269504f

__device__ __forceinline__ void gload_lds16(const void* g, void* l){
  __builtin_amdgcn_global_load_lds((__attribute__((address_space(1))) unsigned int*)g,
                                   (__attribute__((address_space(3))) unsigned int*)l,
                                   16, 0, 0);
}

__device__ __forceinline__ float fastexp2(float x){
#if __has_builtin(__builtin_amdgcn_exp2f)
  return __builtin_amdgcn_exp2f(x);
#else
  return exp2f(x);
#endif
}

// swizzle key for 128B-row tiles (8 chunks of 16B per row)
__device__ __forceinline__ int swzkey(int row){ return (row&7) ^ ((row>>3)&7); }

// ---------------- fused: weight->fp16 prep (ids 0..5119) + LayerNorm1 (ids 5120..7167) ----------------
__global__ __launch_bounds__(256) void prep_ln(const float* __restrict__ Wq,
                                               const float* __restrict__ Wk,
                                               const float* __restrict__ Wv,
                                               const float* __restrict__ W1,
                                               const float* __restrict__ W2,
                                               h16* __restrict__ wqkv,
                                               h16* __restrict__ w1h,
                                               h16* __restrict__ w2h,
                                               const float* __restrict__ x,
                                               const float* __restrict__ sc,
                                               const float* __restrict__ bi,
                                               h16* __restrict__ xn_h){
  int id = blockIdx.x;
  int t = threadIdx.x;
  if (id < 5120){
    const int nW = DMODEL*DMODEL;
    int r = id >> 10;
    int i = ((id & 1023)*256 + t)*4;
    const float* src = (r==0) ? Wq : (r==1) ? Wk : (r==2) ? Wv : (r==3) ? W1 : W2;
    h16* dst = (r==0) ? wqkv : (r==1) ? (wqkv+nW) : (r==2) ? (wqkv+2*nW) : (r==3) ? w1h : w2h;
    float4 v = *reinterpret_cast<const float4*>(src + i);
    h16x4 o; o[0]=(h16)v.x; o[1]=(h16)v.y; o[2]=(h16)v.z; o[3]=(h16)v.w;
    *reinterpret_cast<h16x4*>(dst + i) = o;
    return;
  }
  int row = (id - 5120)*4 + (t>>6);
  int l = t & 63;
  size_t rbase = (size_t)row*DMODEL;
  float v[16];
  #pragma unroll
  for (int q=0;q<4;++q){
    float4 tt = *reinterpret_cast<const float4*>(x + rbase + q*256 + l*4);
    v[q*4]=tt.x; v[q*4+1]=tt.y; v[q*4+2]=tt.z; v[q*4+3]=tt.w;
  }
  float s=0.f, ss=0.f;
  #pragma unroll
  for (int j=0;j<16;++j){ s += v[j]; ss += v[j]*v[j]; }
  #pragma unroll
  for (int m=1;m<64;m<<=1){ s += __shfl_xor(s,m); ss += __shfl_xor(ss,m); }
  float mu  = s * (1.0f/DMODEL);
  float var = fmaxf(ss * (1.0f/DMODEL) - mu*mu, 0.0f);
  float r = rsqrtf(var + EPS);
  #pragma unroll
  for (int q=0;q<4;++q){
    float4 g = *reinterpret_cast<const float4*>(sc + q*256 + l*4);
    float4 b = *reinterpret_cast<const float4*>(bi + q*256 + l*4);
    h16x4 oh;
    oh[0] = (h16)((v[q*4  ]-mu)*r*g.x + b.x);
    oh[1] = (h16)((v[q*4+1]-mu)*r*g.y + b.y);
    oh[2] = (h16)((v[q*4+2]-mu)*r*g.z + b.z);
    oh[3] = (h16)((v[q*4+3]-mu)*r*g.w + b.w);
    *reinterpret_cast<h16x4*>(xn_h + rbase + q*256 + l*4) = oh;
  }
}

// ---------------- fused QKV GEMM (fp16, BK=64, double-buffered, XCD-stripe bn-major) ----------------
__global__ __launch_bounds__(256) void gemm_qkv(const h16* __restrict__ xn,
                                                const h16* __restrict__ wqkv,
                                                h16* __restrict__ qT,
                                                h16* __restrict__ kR,
                                                h16* __restrict__ vT){
  const int K = DMODEL;
  __shared__ h16 As[2][128*64], Bs[2][128*64];
  int id = blockIdx.x;
  int xcd = id & 7, j = id >> 3;
  int bn = j >> 3;                       // bn-major: A-stripe (2MB) stays L2-resident
  int bm = xcd*8 + (j & 7);
  int t = threadIdx.x, l = t&63, w = t>>6;
  int wr = w>>1, wc = w&1;
  const h16* Bsrc = wqkv + (size_t)bn*128*K;

  f32x4 acc[4][4];
  #pragma unroll
  for (int m=0;m<4;++m)
    #pragma unroll
    for (int n=0;n<4;++n)
      #pragma unroll
      for (int i=0;i<4;++i) acc[m][n][i] = 0.0f;

  #define QSTAGE(bb, k0)                                                          \
    { _Pragma("unroll")                                                           \
      for (int i_=0;i_<4;++i_){                                                   \
        int slot = i_*256 + t;                                                    \
        int row = slot>>3, pc = slot&7;                                           \
        int lc = pc ^ swzkey(row);                                                \
        gload_lds16(xn + (size_t)(bm*128 + row)*K + (k0) + lc*8, &As[bb][slot*8]);\
        gload_lds16(Bsrc + (size_t)row*K + (k0) + lc*8, &Bs[bb][slot*8]);         \
      } }

  const int nk = K/64;
  QSTAGE(0, 0);
  int cur = 0;
  for (int kt=0; kt<nk; ++kt){
    __syncthreads();                 // vmcnt drain: buf[cur] staged; prev compute done
    if (kt+1 < nk) QSTAGE(cur^1, (kt+1)*64);
    #pragma unroll
    for (int ks=0; ks<2; ++ks){
      f16x8 af[4], bf[4];
      #pragma unroll
      for (int m=0;m<4;++m){
        int row = wr*64 + m*16 + (l&15);
        int cp = (ks*4 + (l>>4)) ^ swzkey(row);
        af[m] = *reinterpret_cast<const f16x8*>(&As[cur][row*64 + cp*8]);
      }
      #pragma unroll
      for (int n=0;n<4;++n){
        int row = wc*64 + n*16 + (l&15);
        int cp = (ks*4 + (l>>4)) ^ swzkey(row);
        bf[n] = *reinterpret_cast<const f16x8*>(&Bs[cur][row*64 + cp*8]);
      }
      __builtin_amdgcn_s_setprio(1);
      #pragma unroll
      for (int m=0;m<4;++m)
        #pragma unroll
        for (int n=0;n<4;++n)
          acc[m][n] = __builtin_amdgcn_mfma_f32_16x16x32_f16(af[m], bf[n], acc[m][n], 0,0,0);
      __builtin_amdgcn_s_setprio(0);
    }
    cur ^= 1;
  }

  // epilogue
  const bool isK = (bn >= 8 && bn < 16);
  const bool isQ = (bn < 8);
  #pragma unroll
  for (int m=0;m<4;++m){
    int row0 = bm*128 + wr*64 + m*16 + ((l>>4)<<2);
    int b = row0 >> 11, s0 = row0 & 2047;
    #pragma unroll
    for (int n=0;n<4;++n){
      int col = bn*128 + wc*64 + n*16 + (l&15);
      int dg = col & 1023;
      int hh = dg >> 6, dh = dg & 63;
      if (isK){
        #pragma unroll
        for (int i=0;i<4;++i)
          kR[((size_t)(b*NHEAD + hh)*SEQ + s0 + i)*DH + dh] = (h16)acc[m][n][i];
      } else {
        h16x4 ov;
        #pragma unroll
        for (int i=0;i<4;++i){
          float vv = acc[m][n][i];
          if (isQ) vv *= LOG2E;
          ov[i] = (h16)vv;
        }
        // sigma-permute s for V: within 32-group, pos = (c&3) + (c>>2)*8 + h*4
        int s0p = isQ ? s0 : ((s0 & ~31) + (((s0>>2)&3)<<3) + (((s0>>4)&1)<<2));
        h16* dst = (isQ ? qT : vT) + ((size_t)(b*NHEAD + hh)*DH + dh)*SEQ + s0p;
        *reinterpret_cast<h16x4*>(dst) = ov;
      }
    }
  }
}

// ---------------- fp16 GEMM (FFN, BK=64, double-buffered, XCD-stripe bn-major) ----------------
template<bool RELU, bool RES, bool OUTF32>
__global__ __launch_bounds__(256) void gemm_ffn(const h16* __restrict__ A,
                                                const h16* __restrict__ W,
                                                const float* __restrict__ bias,
                                                const h16* __restrict__ resid,
                                                void* __restrict__ outp,
                                                int M, int N, int K){
  __shared__ h16 As[2][128*64];
  __shared__ h16 Bs[2][128*64];
  int id = blockIdx.x;
  int xcd = id & 7, j = id >> 3;
  int spb = (M>>7)>>3;                   // stripe blocks per xcd (8)
  int bn = j / spb;                      // bn-major
  int bm = xcd*spb + (j - bn*spb);
  int t = threadIdx.x, l = t&63, w = t>>6;
  int wr = w>>1, wc = w&1;
  f32x4 acc[4][4];
  #pragma unroll
  for (int m=0;m<4;++m)
    #pragma unroll
    for (int n=0;n<4;++n)
      #pragma unroll
      for (int i=0;i<4;++i) acc[m][n][i] = 0.0f;

  #define FSTAGE(bb, k0)                                                          \
    { _Pragma("unroll")                                                           \
      for (int i_=0;i_<4;++i_){                                                   \
        int slot = i_*256 + t;                                                    \
        int row = slot>>3, pc = slot&7;                                           \
        int lc = pc ^ swzkey(row);                                                \
        gload_lds16(A + (size_t)(bm*128 + row)*K + (k0) + lc*8, &As[bb][slot*8]); \
        gload_lds16(W + (size_t)(bn*128 + row)*K + (k0) + lc*8, &Bs[bb][slot*8]); \
      } }

  const int nk = K/64;
  FSTAGE(0, 0);
  int cur = 0;
  for (int kt=0; kt<nk; ++kt){
    __syncthreads();
    if (kt+1 < nk) FSTAGE(cur^1, (kt+1)*64);
    #pragma unroll
    for (int ks=0; ks<2; ++ks){
      f16x8 af[4], bf[4];
      #pragma unroll
      for (int m=0;m<4;++m){
        int row = wr*64 + m*16 + (l&15);
        int cp = (ks*4 + (l>>4)) ^ swzkey(row);
        af[m] = *reinterpret_cast<const f16x8*>(&As[cur][row*64 + cp*8]);
      }
      #pragma unroll
      for (int n=0;n<4;++n){
        int row = wc*64 + n*16 + (l&15);
        int cp = (ks*4 + (l>>4)) ^ swzkey(row);
        bf[n] = *reinterpret_cast<const f16x8*>(&Bs[cur][row*64 + cp*8]);
      }
      __builtin_amdgcn_s_setprio(1);
      #pragma unroll
      for (int m=0;m<4;++m)
        #pragma unroll
        for (int n=0;n<4;++n)
          acc[m][n] = __builtin_amdgcn_mfma_f32_16x16x32_f16(af[m], bf[n], acc[m][n], 0,0,0);
      __builtin_amdgcn_s_setprio(0);
    }
    cur ^= 1;
  }

  #pragma unroll
  for (int m=0;m<4;++m){
    int row0 = bm*128 + wr*64 + m*16 + ((l>>4)<<2);
    #pragma unroll
    for (int n=0;n<4;++n){
      int col = bn*128 + wc*64 + n*16 + (l&15);
      float bv = bias[col];
      #pragma unroll
      for (int i=0;i<4;++i){
        float vv = acc[m][n][i] + bv;
        if (RELU) vv = fmaxf(vv, 0.0f);
        size_t off = (size_t)(row0+i)*N + col;
        if (RES) vv += (float)resid[off];
        if (OUTF32) ((float*)outp)[off] = vv;
        else        ((h16*)outp)[off] = (h16)vv;
      }
    }
  }
}

// ---------------- flash attention v10 (r15/r17-proven): ones-MFMA psum, shuffle-free defer ----------------
#define QBLK 256
#define KBLK 64
#define RESC_THR_L2 11.5415603f    // 8 * log2(e)
#define NROWS (BH*8*256)           // 131072 rows per half

__global__ __launch_bounds__(512, 2) void attn_split(const h16* __restrict__ qT,
                                                     const h16* __restrict__ kR,
                                                     const h16* __restrict__ vT,
                                                     h16* __restrict__ outP0,
                                                     h16* __restrict__ outP1,
                                                     float2* __restrict__ lm){
  int id = blockIdx.x;
  int bh   = (id & 7) + ((id >> 7) << 3);   // XCD-aware: same bh stays on one XCD
  int qb   = (id >> 3) & 7;
  int half = (id >> 6) & 1;
  int t = threadIdx.x, l = t&63, w = t>>6;
  int g = l>>4;

  const size_t hbase = (size_t)bh * SEQ * DH;
  const h16* khb = kR + hbase + (size_t)half*(SEQ/2)*DH;   // [s][64], row offset
  const h16* qtb = qT + hbase;                             // [64][s]
  const h16* vtb = vT + hbase + half*(SEQ/2);              // [64][s], col offset
  int q0 = qb*QBLK + w*32;

  // Q fragments (B-operand), log2e-scaled
  f16x8 qf[2][2];
  #pragma unroll
  for (int qs=0;qs<2;++qs)
    #pragma unroll
    for (int kc=0;kc<2;++kc)
      #pragma unroll
      for (int j=0;j<8;++j)
        qf[qs][kc][j] = qtb[(size_t)(kc*32 + g*8 + j)*SEQ + q0 + qs*16 + (l&15)];

  __shared__ h16 Kh2[2][KBLK*64];
  __shared__ h16 Vt2[2][KBLK*64];

  // hoisted LDS byte-offsets: identical formula for K (st) and V (dt) reads
  int offs[8];
  #pragma unroll
  for (int kc=0;kc<2;++kc)
    #pragma unroll
    for (int st=0;st<4;++st){
      int rr = st*16 + (l&15);
      offs[kc*4+st] = rr*128 + (((kc*4 + g) ^ swzkey(rr))<<4);
    }

  // hoisted staging source pointers (advance per tile)
  int srow = t>>3, spc = t&7;
  int slc = spc ^ swzkey(srow);
  const h16* ksrc = khb + (size_t)srow*DH + slc*8;
  const h16* vsrc = vtb + (size_t)srow*SEQ + slc*8;

  f32x4 o[2][4];
  #pragma unroll
  for (int qs=0;qs<2;++qs)
    #pragma unroll
    for (int dt=0;dt<4;++dt)
      #pragma unroll
      for (int i=0;i<4;++i) o[qs][dt][i] = 0.0f;
  // psum accumulators via ones-MFMA (full 64-k sum per tile; identical across partner lanes)
  f32x4 lacc[2];
  #pragma unroll
  for (int qs=0;qs<2;++qs)
    #pragma unroll
    for (int i=0;i<4;++i) lacc[qs][i] = 0.0f;
  float m_run[2] = {-3.0e38f, -3.0e38f};

  f16x8 onesA;
  #pragma unroll
  for (int j=0;j<8;++j) onesA[j] = (h16)1.0f;

  #define STAGE(bb)                                  \
    { gload_lds16(ksrc, &Kh2[bb][t*8]);              \
      gload_lds16(vsrc, &Vt2[bb][t*8]);              \
      ksrc += KBLK*DH; vsrc += KBLK; }

  STAGE(0);
  int cur = 0;
  const int NT = SEQ/2/KBLK;     // 16 tiles per half
  for (int kt=0; kt<NT; ++kt){
    __syncthreads();
    if (kt+1 < NT) STAGE(cur^1);

    char* KhB = (char*)&Kh2[cur][0];
    char* VtB = (char*)&Vt2[cur][0];

    // ---- S^T = K.Q^T (fp16, log2 domain) ----
    f32x4 sc[2][4];
    #pragma unroll
    for (int qs=0;qs<2;++qs)
      #pragma unroll
      for (int st=0;st<4;++st)
        #pragma unroll
        for (int i=0;i<4;++i) sc[qs][st][i] = 0.0f;

    #pragma unroll
    for (int kc=0;kc<2;++kc)
      #pragma unroll
      for (int st=0;st<4;++st){
        f16x8 kf = *reinterpret_cast<const f16x8*>(KhB + offs[kc*4+st]);
        __builtin_amdgcn_s_setprio(1);
        sc[0][st] = __builtin_amdgcn_mfma_f32_16x16x32_f16(kf, qf[0][kc], sc[0][st], 0,0,0);
        sc[1][st] = __builtin_amdgcn_mfma_f32_16x16x32_f16(kf, qf[1][kc], sc[1][st], 0,0,0);
        __builtin_amdgcn_s_setprio(0);
      }

    // ---- defer check: per-lane local max only (wave-AND == per-row check) ----
    float lmax[2];
    #pragma unroll
    for (int qs=0;qs<2;++qs){
      const float* s = (const float*)&sc[qs][0];
      float m0 = fmaxf(s[0], s[1]);
      #pragma unroll
      for (int j=2;j<16;j+=2) m0 = fmaxf(fmaxf(m0, s[j]), s[j+1]);  // folds to v_max3
      lmax[qs] = m0;
    }
    bool defer = (__all((lmax[0] <= m_run[0] + RESC_THR_L2) &&
                        (lmax[1] <= m_run[1] + RESC_THR_L2)) != 0);
    if (!defer){
      #pragma unroll
      for (int qs=0;qs<2;++qs){
        float m0 = lmax[qs];
        m0 = fmaxf(m0, __shfl_xor(m0, 16));
        m0 = fmaxf(m0, __shfl_xor(m0, 32));
        float mn = fmaxf(m_run[qs], m0);
        float scl = fastexp2(m_run[qs] - mn);
        m_run[qs] = mn;
        #pragma unroll
        for (int dt=0;dt<4;++dt)
          #pragma unroll
          for (int i=0;i<4;++i) o[qs][dt][i] *= scl;
        #pragma unroll
        for (int i=0;i<4;++i) lacc[qs][i] *= scl;
      }
    }

    // ---- P = 2^(s - m_run), packed to fp16 ----
    union { unsigned u[4]; f16x8 v; } pfu[2][2];
    #pragma unroll
    for (int qs=0;qs<2;++qs){
      float mn = m_run[qs];
      const float* s = (const float*)&sc[qs][0];
      #pragma unroll
      for (int kc=0;kc<2;++kc)
        #pragma unroll
        for (int j=0;j<4;++j){
          float p0 = fastexp2(s[kc*8+2*j]   - mn);
          float p1 = fastexp2(s[kc*8+2*j+1] - mn);
          union { fp16v2 v2; unsigned u; } c;
          c.v2 = __builtin_amdgcn_cvt_pkrtz(p0, p1);
          pfu[qs][kc].u[j] = c.u;
        }
    }

    // ---- PV + psum: O^T += V^T . P^T; lacc += ones . P^T ----
    #pragma unroll
    for (int kc=0;kc<2;++kc){
      __builtin_amdgcn_s_setprio(1);
      lacc[0] = __builtin_amdgcn_mfma_f32_16x16x32_f16(onesA, pfu[0][kc].v, lacc[0], 0,0,0);
      lacc[1] = __builtin_amdgcn_mfma_f32_16x16x32_f16(onesA, pfu[1][kc].v, lacc[1], 0,0,0);
      __builtin_amdgcn_s_setprio(0);
      #pragma unroll
      for (int dt=0;dt<4;++dt){
        f16x8 vf = *reinterpret_cast<const f16x8*>(VtB + offs[kc*4+dt]);
        __builtin_amdgcn_s_setprio(1);
        o[0][dt] = __builtin_amdgcn_mfma_f32_16x16x32_f16(vf, pfu[0][kc].v, o[0][dt], 0,0,0);
        o[1][dt] = __builtin_amdgcn_mfma_f32_16x16x32_f16(vf, pfu[1][kc].v, o[1][dt], 0,0,0);
        __builtin_amdgcn_s_setprio(0);
      }
    }
    cur ^= 1;
  }

  // epilogue: lacc already holds full row-sum (no cross-lane reduce needed)
  h16* outP = half ? outP1 : outP0;
  int rowbase = (bh*8 + qb)*256 + w*32;
  #pragma unroll
  for (int qs=0;qs<2;++qs){
    float lt = lacc[qs][0];
    float inv = 1.0f / lt;
    int row = rowbase + qs*16 + (l&15);
    #pragma unroll
    for (int dt=0;dt<4;++dt){
      h16x4 ov;
      #pragma unroll
      for (int i=0;i<4;++i) ov[i] = (h16)(o[qs][dt][i] * inv);
      *reinterpret_cast<h16x4*>(outP + (size_t)row*64 + dt*16 + (g<<2)) = ov;
    }
    if (l < 16)
      lm[half*NROWS + row] = make_float2(m_run[qs], lt);
  }
}

// ---------------- fused combine + LayerNorm2 (fp16 residual in, fp16 out) ----------------
__global__ __launch_bounds__(256) void ln2_combine(const h16* __restrict__ xn,
                                                   const h16* __restrict__ p0,
                                                   const h16* __restrict__ p1,
                                                   const float2* __restrict__ lm,
                                                   const float* __restrict__ sc,
                                                   const float* __restrict__ bi,
                                                   h16* __restrict__ oh16){
  int token = blockIdx.x*4 + (threadIdx.x>>6);
  int l = threadIdx.x & 63;
  int b = token >> 11, qb = (token >> 8) & 7, r = token & 255;
  int hh = l >> 2;                       // head owned by this lane group
  int rowg = ((b*NHEAD + hh)*8 + qb)*256 + r;
  float2 A = lm[rowg];
  float2 B = lm[NROWS + rowg];
  float ms = fmaxf(A.x, B.x);
  float w0 = A.y * fastexp2(A.x - ms);
  float w1 = B.y * fastexp2(B.x - ms);
  float inv = 1.0f / (w0 + w1);
  w0 *= inv; w1 *= inv;

  // lane's 16 contiguous d-elements: global d = l*16
  const f16x8* q0 = reinterpret_cast<const f16x8*>(p0 + (size_t)rowg*64 + (l&3)*16);
  const f16x8* q1 = reinterpret_cast<const f16x8*>(p1 + (size_t)rowg*64 + (l&3)*16);
  size_t base = (size_t)token*DMODEL + l*16;
  float v[16];
  #pragma unroll
  for (int c=0;c<2;++c){
    f16x8 a = q0[c], bb = q1[c];
    #pragma unroll
    for (int j=0;j<8;++j)
      v[c*8+j] = (float)a[j]*w0 + (float)bb[j]*w1;
  }
  #pragma unroll
  for (int c=0;c<2;++c){
    f16x8 xv = *reinterpret_cast<const f16x8*>(xn + base + c*8);
    #pragma unroll
    for (int j=0;j<8;++j)
      v[c*8+j] += (float)xv[j];
  }

  float s=0.f, ss=0.f;
  #pragma unroll
  for (int j=0;j<16;++j){ s += v[j]; ss += v[j]*v[j]; }
  #pragma unroll
  for (int m=1;m<64;m<<=1){ s += __shfl_xor(s,m); ss += __shfl_xor(ss,m); }
  float mu  = s * (1.0f/DMODEL);
  float var = fmaxf(ss * (1.0f/DMODEL) - mu*mu, 0.0f);
  float rr = rsqrtf(var + EPS);
  #pragma unroll
  for (int q=0;q<4;++q){
    float4 g = *reinterpret_cast<const float4*>(sc + l*16 + q*4);
    float4 bb = *reinterpret_cast<const float4*>(bi + l*16 + q*4);
    h16x4 oh;
    oh[0] = (h16)((v[q*4  ]-mu)*rr*g.x + bb.x);
    oh[1] = (h16)((v[q*4+1]-mu)*rr*g.y + bb.y);
    oh[2] = (h16)((v[q*4+2]-mu)*rr*g.z + bb.z);
    oh[3] = (h16)((v[q*4+3]-mu)*rr*g.w + bb.w);
    *reinterpret_cast<h16x4*>(oh16 + base + q*4) = oh;
  }
}

// ---------------- launch ----------------
extern "C" void kernel_launch(void* const* d_in, const int* in_sizes, int n_in,
                              void* d_out, int out_size, void* d_ws, size_t ws_size,
                              hipStream_t stream){
  (void)in_sizes; (void)n_in; (void)out_size; (void)ws_size;
  const float* x    = (const float*)d_in[0];
  const float* Wq   = (const float*)d_in[1];
  const float* Wk   = (const float*)d_in[2];
  const float* Wv   = (const float*)d_in[3];
  const float* W1   = (const float*)d_in[4];
  const float* b1   = (const float*)d_in[5];
  const float* W2   = (const float*)d_in[6];
  const float* b2   = (const float*)d_in[7];
  const float* ln1s = (const float*)d_in[8];
  const float* ln1b = (const float*)d_in[9];
  const float* ln2s = (const float*)d_in[10];
  const float* ln2b = (const float*)d_in[11];

  char* ws = (char*)d_ws;
  h16* part0     = (h16*)ws;    ws += (size_t)NTOK*DMODEL*2;
  h16* part1     = (h16*)ws;    ws += (size_t)NTOK*DMODEL*2;
  h16* xn_h      = (h16*)ws;    ws += (size_t)NTOK*DMODEL*2;
  h16* qT_h      = (h16*)ws;    ws += (size_t)NTOK*DMODEL*2;
  h16* k_h       = (h16*)ws;    ws += (size_t)NTOK*DMODEL*2;
  h16* vT_h      = (h16*)ws;    ws += (size_t)NTOK*DMODEL*2;
  h16* xt_h      = (h16*)ws;    ws += (size_t)NTOK*DMODEL*2;
  h16* h_h       = (h16*)ws;    ws += (size_t)NTOK*DMODEL*2;
  h16* wqkv_h    = (h16*)ws;    ws += (size_t)3*DMODEL*DMODEL*2;
  h16* w1h       = (h16*)ws;    ws += (size_t)DMODEL*DMODEL*2;
  h16* w2h       = (h16*)ws;    ws += (size_t)DMODEL*DMODEL*2;
  float2* lm     = (float2*)ws; ws += (size_t)2*NROWS*8;

  prep_ln<<<5120 + NTOK/4, 256, 0, stream>>>(Wq, Wk, Wv, W1, W2, wqkv_h, w1h, w2h,
                                             x, ln1s, ln1b, xn_h);

  gemm_qkv<<<3*DMODEL/128 * (NTOK/128), 256, 0, stream>>>(
      xn_h, wqkv_h, qT_h, k_h, vT_h);

  attn_split<<<BH*(SEQ/QBLK)*2, 512, 0, stream>>>(qT_h, k_h, vT_h, part0, part1, lm);

  ln2_combine<<<NTOK/4, 256, 0, stream>>>(xn_h, part0, part1, lm,
                                          ln2s, ln2b, xt_h);

  gemm_ffn<true,false,false><<<(DMODEL/128) * (NTOK/128), 256, 0, stream>>>(
      xt_h, w1h, b1, nullptr, h_h, NTOK, DMODEL, DMODEL);

  gemm_ffn<false,true,true><<<(DMODEL/128) * (NTOK/128), 256, 0, stream>>>(
      h_h, w2h, b2, xt_h, d_out, NTOK, DMODEL, DMODEL);
}